// Round 1
// baseline (160.710 us; speedup 1.0000x reference)
//
#include <hip/hip_runtime.h>

#define DI __device__ __forceinline__

using f32x4  = __attribute__((ext_vector_type(4))) float;
using bf16x8 = __attribute__((ext_vector_type(8))) __bf16;
using u16x4  = __attribute__((ext_vector_type(4))) unsigned short;
using u32x4  = __attribute__((ext_vector_type(4))) unsigned int;

constexpr int NNODE = 8192;

DI unsigned short f2bf(float f) {
    unsigned int u = __builtin_bit_cast(unsigned int, f);
    u += 0x7fffu + ((u >> 16) & 1u);   // round-to-nearest-even
    return (unsigned short)(u >> 16);
}
DI float bf2f(unsigned short s) {
    return __builtin_bit_cast(float, (unsigned int)s << 16);
}

// swizzled LDS byte offsets (G4: break row-stride bank conflicts)
DI int swz256(int r, int cb) { return r * 256 + (cb ^ ((r & 15) << 4)); } // 256B rows (K=128 bf16)
DI int swz128(int r, int cb) { return r * 128 + (cb ^ ((r & 7) << 4)); }  // 128B rows (K=64 bf16)

// ---------------- weight prep: transpose to [n][k], split into bf16 hi/lo ----------------
__global__ void prep_w(const float* __restrict__ W_emb, const float* __restrict__ W_e,
                       const float* __restrict__ W_gc1, const float* __restrict__ W_gc2,
                       unsigned short* __restrict__ WembT_hi, unsigned short* __restrict__ WembT_lo,
                       unsigned short* __restrict__ WcatT_hi, unsigned short* __restrict__ WcatT_lo,
                       unsigned short* __restrict__ Wg2T_hi, unsigned short* __restrict__ Wg2T_lo)
{
    int gid = blockIdx.x * 256 + threadIdx.x;
    if (gid >= 576 * 128) return;
    int k = gid & 127, n = gid >> 7;
    float v;
    unsigned short *dh, *dl;
    if (n < 128) {                       // W_emb^T
        v = W_emb[k * 128 + n];
        dh = WembT_hi + n * 128 + k; dl = WembT_lo + n * 128 + k;
    } else if (n < 512) {                // [W_e_src | W_e_dst | W_gc1]^T
        int m = n - 128;
        if (m < 128)      v = W_e[k * 128 + m];
        else if (m < 256) v = W_e[(k + 128) * 128 + (m - 128)];
        else              v = W_gc1[k * 128 + (m - 256)];
        dh = WcatT_hi + m * 128 + k; dl = WcatT_lo + m * 128 + k;
    } else {                             // W_gc2^T padded 40 -> 64
        int c = n - 512;
        v = (c < 40) ? W_gc2[k * 40 + c] : 0.f;
        dh = Wg2T_hi + c * 128 + k; dl = Wg2T_lo + c * 128 + k;
    }
    unsigned short hi = f2bf(v);
    *dh = hi;
    *dl = f2bf(v - bf2f(hi));
}

// ---------------- small split-bf16 GEMM: M=8192, K=128, N-chunk per block ----------------
// AKIND: 0 = A is fp32 (split in-kernel), 1 = A given as hi/lo bf16
// OUTKIND: 0 = write hi/lo bf16 row-major (+bias)   [gemm_h]
//          1 = cols<128 -> fp32 row-major (s_src), cols>=128 -> bf16 transposed [gemm_s]
//          2 = bf16 transposed [gemm_g2]
template<int NCHUNK, int AKIND, int OUTKIND>
__global__ __launch_bounds__(256) void small_gemm(
    const float* __restrict__ Af32,
    const unsigned short* __restrict__ A_hi, const unsigned short* __restrict__ A_lo,
    const unsigned short* __restrict__ Bt_hi, const unsigned short* __restrict__ Bt_lo,
    const float* __restrict__ bias,
    unsigned short* __restrict__ out_hi, unsigned short* __restrict__ out_lo,
    float* __restrict__ out_s,
    unsigned short* __restrict__ out_t)
{
    __shared__ unsigned short Ah[64 * 128], Al[64 * 128];
    __shared__ unsigned short Bh[NCHUNK * 128], Bl[NCHUNK * 128];
    char* Ahc = (char*)Ah; char* Alc = (char*)Al;
    char* Bhc = (char*)Bh; char* Blc = (char*)Bl;

    const int tid = threadIdx.x;
    const int r0 = blockIdx.x * 64;
    const int n0 = blockIdx.y * NCHUNK;

    if constexpr (AKIND == 0) {
        #pragma unroll
        for (int p = 0; p < 8; ++p) {
            int idx = tid + 256 * p, r = idx >> 5, c4 = idx & 31;
            f32x4 v = *(const f32x4*)(Af32 + (size_t)(r0 + r) * 128 + c4 * 4);
            u16x4 ph, pl;
            #pragma unroll
            for (int j = 0; j < 4; ++j) {
                unsigned short hi = f2bf(v[j]);
                ph[j] = hi; pl[j] = f2bf(v[j] - bf2f(hi));
            }
            *(u16x4*)(Ahc + swz256(r, c4 * 8)) = ph;
            *(u16x4*)(Alc + swz256(r, c4 * 8)) = pl;
        }
    } else {
        #pragma unroll
        for (int p = 0; p < 4; ++p) {
            int idx = tid + 256 * p, r = idx >> 4, c = idx & 15;
            u32x4 vh = *(const u32x4*)(A_hi + (size_t)(r0 + r) * 128 + c * 8);
            u32x4 vl = *(const u32x4*)(A_lo + (size_t)(r0 + r) * 128 + c * 8);
            *(u32x4*)(Ahc + swz256(r, c * 16)) = vh;
            *(u32x4*)(Alc + swz256(r, c * 16)) = vl;
        }
    }
    #pragma unroll
    for (int p = 0; p < NCHUNK / 16; ++p) {
        int idx = tid + 256 * p, r = idx >> 4, c = idx & 15;
        u32x4 vh = *(const u32x4*)(Bt_hi + (size_t)(n0 + r) * 128 + c * 8);
        u32x4 vl = *(const u32x4*)(Bt_lo + (size_t)(n0 + r) * 128 + c * 8);
        *(u32x4*)(Bhc + swz256(r, c * 16)) = vh;
        *(u32x4*)(Blc + swz256(r, c * 16)) = vl;
    }
    __syncthreads();

    const int lane = tid & 63, wid = tid >> 6;
    const int lrow = lane & 15, lkb = (lane >> 4) * 16;
    constexpr int FN = NCHUNK / 16;
    f32x4 acc[FN];
    #pragma unroll
    for (int i = 0; i < FN; ++i) acc[i] = f32x4{0.f, 0.f, 0.f, 0.f};

    const int arow = wid * 16 + lrow;
    #pragma unroll
    for (int kk = 0; kk < 4; ++kk) {
        bf16x8 ah = *(const bf16x8*)(Ahc + swz256(arow, kk * 64 + lkb));
        bf16x8 al = *(const bf16x8*)(Alc + swz256(arow, kk * 64 + lkb));
        #pragma unroll
        for (int nf = 0; nf < FN; ++nf) {
            bf16x8 bh = *(const bf16x8*)(Bhc + swz256(nf * 16 + lrow, kk * 64 + lkb));
            bf16x8 bl = *(const bf16x8*)(Blc + swz256(nf * 16 + lrow, kk * 64 + lkb));
            acc[nf] = __builtin_amdgcn_mfma_f32_16x16x32_bf16(ah, bh, acc[nf], 0, 0, 0);
            acc[nf] = __builtin_amdgcn_mfma_f32_16x16x32_bf16(ah, bl, acc[nf], 0, 0, 0);
            acc[nf] = __builtin_amdgcn_mfma_f32_16x16x32_bf16(al, bh, acc[nf], 0, 0, 0);
        }
    }

    const int rowb = r0 + wid * 16 + ((lane >> 4) << 2);
    #pragma unroll
    for (int nf = 0; nf < FN; ++nf) {
        const int col = n0 + nf * 16 + lrow;
        if constexpr (OUTKIND == 0) {
            float bv = bias[col];
            #pragma unroll
            for (int j = 0; j < 4; ++j) {
                float v = acc[nf][j] + bv;
                unsigned short hi = f2bf(v);
                out_hi[(size_t)(rowb + j) * 128 + col] = hi;
                out_lo[(size_t)(rowb + j) * 128 + col] = f2bf(v - bf2f(hi));
            }
        } else if constexpr (OUTKIND == 1) {
            if (col < 128) {
                #pragma unroll
                for (int j = 0; j < 4; ++j)
                    out_s[(size_t)(rowb + j) * 128 + col] = acc[nf][j];
            } else {
                u16x4 pk = { f2bf(acc[nf][0]), f2bf(acc[nf][1]), f2bf(acc[nf][2]), f2bf(acc[nf][3]) };
                *(u16x4*)(out_t + (size_t)(col - 128) * NNODE + rowb) = pk;
            }
        } else {
            u16x4 pk = { f2bf(acc[nf][0]), f2bf(acc[nf][1]), f2bf(acc[nf][2]), f2bf(acc[nf][3]) };
            *(u16x4*)(out_t + (size_t)col * NNODE + rowb) = pk;
        }
    }
}

// ---------------- big adj GEMM: T[i][n] = sum_j adj[i][j] * Bt[n][j], optional deg ----------------
template<int NCOLS, bool DEG>
__global__ __launch_bounds__(512) void adj_gemm(
    const float* __restrict__ adj,
    const unsigned short* __restrict__ Bt,   // [NCOLS][8192] bf16
    float* __restrict__ Tpart,               // [2][8192][NCOLS] fp32
    float* __restrict__ deg)
{
    __shared__ unsigned short A_lds[2][64 * 64];
    __shared__ unsigned short B_lds[2][NCOLS * 64];

    const int tid = threadIdx.x;
    const int r0 = blockIdx.x * 64;
    const int ks = blockIdx.y;
    constexpr int KLEN = NNODE / 2;
    constexpr int NT = KLEN / 64;
    const int kbase = ks * KLEN;

    constexpr int NB = NCOLS / 64;   // 16B B-chunks per thread per tile
    f32x4 areg[2];
    u32x4 breg[NB];
    float dsum0 = 0.f, dsum1 = 0.f;
    const int ar0 = tid >> 4, ac4 = tid & 15;

    const int lane = tid & 63, wid = tid >> 6;
    constexpr int FM = (NCOLS == 256) ? 2 : 1;
    constexpr int FN = (NCOLS == 256) ? 4 : 2;
    const int wr = (NCOLS == 256) ? (wid >> 2) : (wid >> 1);
    const int wc = (NCOLS == 256) ? (wid & 3) : (wid & 1);
    const int row_w = wr * FM * 16, col_w = wc * FN * 16;
    const int lrow = lane & 15, lkb = (lane >> 4) * 16;

    f32x4 acc[FM][FN];
    #pragma unroll
    for (int fm = 0; fm < FM; ++fm)
        #pragma unroll
        for (int fn = 0; fn < FN; ++fn) acc[fm][fn] = f32x4{0.f, 0.f, 0.f, 0.f};

    auto loadG = [&](int t) {
        const int kt = kbase + t * 64;
        #pragma unroll
        for (int p = 0; p < 2; ++p) {
            areg[p] = *(const f32x4*)(adj + (size_t)(r0 + ar0 + 32 * p) * NNODE + kt + ac4 * 4);
            if (DEG) {
                float s = areg[p][0] + areg[p][1] + areg[p][2] + areg[p][3];
                if (p == 0) dsum0 += s; else dsum1 += s;
            }
        }
        #pragma unroll
        for (int p = 0; p < NB; ++p) {
            const int idx = tid + 512 * p, n = idx >> 3, c = idx & 7;
            breg[p] = *(const u32x4*)(Bt + (size_t)n * NNODE + kt + c * 8);
        }
    };
    auto storeL = [&](int buf) {
        char* Ac = (char*)(A_lds[buf]);
        char* Bc = (char*)(B_lds[buf]);
        #pragma unroll
        for (int p = 0; p < 2; ++p) {
            u16x4 pk = { f2bf(areg[p][0]), f2bf(areg[p][1]), f2bf(areg[p][2]), f2bf(areg[p][3]) };
            *(u16x4*)(Ac + swz128(ar0 + 32 * p, ac4 * 8)) = pk;
        }
        #pragma unroll
        for (int p = 0; p < NB; ++p) {
            const int idx = tid + 512 * p, n = idx >> 3, c = idx & 7;
            *(u32x4*)(Bc + swz128(n, c * 16)) = breg[p];
        }
    };

    loadG(0);
    storeL(0);
    for (int t = 0; t < NT; ++t) {
        if (t + 1 < NT) loadG(t + 1);      // issue next-tile loads before MFMA (latency overlap)
        __syncthreads();                    // tile t visible in LDS
        const char* Ac = (const char*)(A_lds[t & 1]);
        const char* Bc = (const char*)(B_lds[t & 1]);
        #pragma unroll
        for (int kk = 0; kk < 2; ++kk) {
            bf16x8 a[FM], b[FN];
            #pragma unroll
            for (int fm = 0; fm < FM; ++fm)
                a[fm] = *(const bf16x8*)(Ac + swz128(row_w + fm * 16 + lrow, kk * 64 + lkb));
            #pragma unroll
            for (int fn = 0; fn < FN; ++fn)
                b[fn] = *(const bf16x8*)(Bc + swz128(col_w + fn * 16 + lrow, kk * 64 + lkb));
            #pragma unroll
            for (int fm = 0; fm < FM; ++fm)
                #pragma unroll
                for (int fn = 0; fn < FN; ++fn)
                    acc[fm][fn] = __builtin_amdgcn_mfma_f32_16x16x32_bf16(a[fm], b[fn], acc[fm][fn], 0, 0, 0);
        }
        if (t + 1 < NT) storeL((t + 1) & 1);
    }

    float* outp = Tpart + (size_t)ks * NNODE * NCOLS;
    #pragma unroll
    for (int fm = 0; fm < FM; ++fm) {
        const int grow0 = r0 + row_w + fm * 16 + ((lane >> 4) << 2);
        #pragma unroll
        for (int fn = 0; fn < FN; ++fn) {
            const int gcol = col_w + fn * 16 + lrow;
            #pragma unroll
            for (int j = 0; j < 4; ++j)
                outp[(size_t)(grow0 + j) * NCOLS + gcol] = acc[fm][fn][j];
        }
    }

    if (DEG) {
        __syncthreads();
        float* sc = (float*)(&A_lds[0][0]);   // 4KB scratch inside 8KB buffer
        sc[tid] = dsum0;
        sc[512 + tid] = dsum1;
        __syncthreads();
        if (tid < 64) {
            const int base = (tid < 32) ? tid * 16 : (512 + (tid - 32) * 16);
            float s = 0.f;
            #pragma unroll
            for (int i = 0; i < 16; ++i) s += sc[base + i];
            atomicAdd(deg + r0 + tid, s);
        }
    }
}

// ---------------- fused elementwise: x_e out + h1 = relu split ----------------
__global__ void post1(const float* __restrict__ tA,     // [2][8192][256]
                      const float* __restrict__ s_src,
                      const float* __restrict__ deg,
                      const float* __restrict__ b_e,
                      const float* __restrict__ b_gc1,
                      float* __restrict__ x_e_out,
                      unsigned short* __restrict__ h1_hi, unsigned short* __restrict__ h1_lo)
{
    int gid = blockIdx.x * 256 + threadIdx.x;  // 8192*128
    int i = gid >> 7, c = gid & 127;
    const size_t o = (size_t)i * 256;
    const size_t o2 = (size_t)NNODE * 256 + o;
    float t_sdst = tA[o + c] + tA[o2 + c];
    float t_g1   = tA[o + 128 + c] + tA[o2 + 128 + c];
    x_e_out[gid] = deg[i] * s_src[gid] + t_sdst + b_e[c];
    float h1 = t_g1 + b_gc1[c];
    h1 = h1 > 0.f ? h1 : 0.f;
    unsigned short hi = f2bf(h1);
    h1_hi[gid] = hi;
    h1_lo[gid] = f2bf(h1 - bf2f(hi));
}

// ---------------- log_softmax over 40 classes, one wave per row ----------------
__global__ void logsm(const float* __restrict__ tB,     // [2][8192][64]
                      const float* __restrict__ b_gc2,
                      float* __restrict__ out)
{
    const int wid = threadIdx.x >> 6, lane = threadIdx.x & 63;
    const int row = blockIdx.x * 4 + wid;
    float v = -1e30f;
    if (lane < 40)
        v = tB[(size_t)row * 64 + lane] + tB[(size_t)NNODE * 64 + (size_t)row * 64 + lane] + b_gc2[lane];
    float m = v;
    #pragma unroll
    for (int off = 32; off; off >>= 1) m = fmaxf(m, __shfl_xor(m, off, 64));
    float e = (lane < 40) ? expf(v - m) : 0.f;
    float s = e;
    #pragma unroll
    for (int off = 32; off; off >>= 1) s += __shfl_xor(s, off, 64);
    if (lane < 40) out[(size_t)row * 40 + lane] = v - m - logf(s);
}

extern "C" void kernel_launch(void* const* d_in, const int* in_sizes, int n_in,
                              void* d_out, int out_size, void* d_ws, size_t ws_size,
                              hipStream_t stream)
{
    const float* x     = (const float*)d_in[0];
    const float* adj   = (const float*)d_in[1];
    const float* W_emb = (const float*)d_in[2];
    const float* b_emb = (const float*)d_in[3];
    const float* W_gc1 = (const float*)d_in[4];
    const float* b_gc1 = (const float*)d_in[5];
    const float* W_e   = (const float*)d_in[6];
    const float* b_e   = (const float*)d_in[7];
    const float* W_gc2 = (const float*)d_in[8];
    const float* b_gc2 = (const float*)d_in[9];

    char* p = (char*)d_ws;
    auto take = [&](size_t bytes) { char* q = p; p += (bytes + 255) & ~(size_t)255; return q; };

    unsigned short* WembT_hi = (unsigned short*)take(128 * 128 * 2);
    unsigned short* WembT_lo = (unsigned short*)take(128 * 128 * 2);
    unsigned short* WcatT_hi = (unsigned short*)take(384 * 128 * 2);
    unsigned short* WcatT_lo = (unsigned short*)take(384 * 128 * 2);
    unsigned short* Wg2T_hi  = (unsigned short*)take(64 * 128 * 2);
    unsigned short* Wg2T_lo  = (unsigned short*)take(64 * 128 * 2);
    unsigned short* h_hi     = (unsigned short*)take((size_t)NNODE * 128 * 2);
    unsigned short* h_lo     = (unsigned short*)take((size_t)NNODE * 128 * 2);
    float*          s_src    = (float*)take((size_t)NNODE * 128 * 4);
    unsigned short* B_A      = (unsigned short*)take((size_t)256 * NNODE * 2);
    float*          tA       = (float*)take((size_t)2 * NNODE * 256 * 4);
    float*          deg      = (float*)take((size_t)NNODE * 4);
    // aliases (lifetime-disjoint, single stream => ordered):
    unsigned short* B_B   = (unsigned short*)s_src;  // written after s_src's last read (post1)
    float*          tB    = tA;                      // written after tA's last read (post1)
    unsigned short* h1_hi = h_hi;                    // h consumed by gemm_s before post1 writes h1
    unsigned short* h1_lo = h_lo;

    float* out_ls = (float*)d_out;                       // [8192][40]
    float* x_e    = (float*)d_out + (size_t)NNODE * 40;  // [8192][128]

    hipMemsetAsync(deg, 0, NNODE * sizeof(float), stream);
    prep_w<<<288, 256, 0, stream>>>(W_emb, W_e, W_gc1, W_gc2,
                                    WembT_hi, WembT_lo, WcatT_hi, WcatT_lo, Wg2T_hi, Wg2T_lo);
    // h = x @ W_emb + b_emb   (split-precision)
    small_gemm<128, 0, 0><<<dim3(128, 1), 256, 0, stream>>>(
        x, nullptr, nullptr, WembT_hi, WembT_lo, b_emb, h_hi, h_lo, nullptr, nullptr);
    // [s_src | s_dst^T | g1^T] = h @ [W_e_src | W_e_dst | W_gc1]
    small_gemm<128, 1, 1><<<dim3(128, 3), 256, 0, stream>>>(
        nullptr, h_hi, h_lo, WcatT_hi, WcatT_lo, nullptr, nullptr, nullptr, s_src, B_A);
    // pass A: tA = adj @ [s_dst | g1], deg = adj.sum(1)
    adj_gemm<256, true><<<dim3(128, 2), 512, 0, stream>>>(adj, B_A, tA, deg);
    // x_e out, h1 = relu(adj@g1 + b_gc1) split
    post1<<<4096, 256, 0, stream>>>(tA, s_src, deg, b_e, b_gc1, x_e, h1_hi, h1_lo);
    // g2^T = (h1 @ W_gc2)^T  (cols padded to 64)
    small_gemm<64, 1, 2><<<dim3(128, 1), 256, 0, stream>>>(
        nullptr, h1_hi, h1_lo, Wg2T_hi, Wg2T_lo, nullptr, nullptr, nullptr, nullptr, B_B);
    // pass B: tB = adj @ g2
    adj_gemm<64, false><<<dim3(128, 2), 512, 0, stream>>>(adj, B_B, tB, nullptr);
    // log_softmax(+b_gc2) -> out
    logsm<<<2048, 256, 0, stream>>>(tB, b_gc2, out_ls);
}